// Round 10
// baseline (463.210 us; speedup 1.0000x reference)
//
#include <hip/hip_runtime.h>
#include <hip/hip_bf16.h>
#include <cstdint>

// Problem constants
#define BATCH 2048
#define MF    40                 // num fields
#define DDIM  64                 // embedding dim
#define LDIM  128                // hidden size per CIN layer
#define ROWS  (BATCH * DDIM)     // 131072 (b,d) rows

typedef __attribute__((ext_vector_type(4)))  short    short4_t;
typedef __attribute__((ext_vector_type(8)))  short    short8;
typedef __attribute__((ext_vector_type(8)))  __bf16   bf16x8;
typedef __attribute__((ext_vector_type(2)))  float    floatx2;
typedef __attribute__((ext_vector_type(16))) float    floatx16;

__device__ __forceinline__ unsigned short f32_to_bf16(float f) {
    union { float f; uint32_t u; } v; v.f = f;
    uint32_t u = v.u;
    uint32_t r = (u + 0x7fffu + ((u >> 16) & 1u)) >> 16;   // RNE
    return (unsigned short)r;
}

// raw barrier: execution sync WITHOUT __syncthreads' vmcnt(0)/lgkmcnt(0) drain
__device__ __forceinline__ void barrier_raw() {
    asm volatile("s_barrier" ::: "memory");
}
template <int N> __device__ __forceinline__ void vmwait() {
    if constexpr (N == 0)  asm volatile("s_waitcnt vmcnt(0)"  ::: "memory");
    if constexpr (N == 3)  asm volatile("s_waitcnt vmcnt(3)"  ::: "memory");
    if constexpr (N == 4)  asm volatile("s_waitcnt vmcnt(4)"  ::: "memory");
    if constexpr (N == 10) asm volatile("s_waitcnt vmcnt(10)" ::: "memory");
}

// ---------------------------------------------------------------------------
// W prep (UNCHANGED layout — A/B fragment layouts are symmetric on gfx950):
//   Wt[m][kk][cb][lane][j] = W[m][ kk*16 + (lane>>5)*8 + j ][ cb*32 + (lane&31) ]
// Used this round as the MFMA *A* operand: A[i=l=lane&31][k=h].
// ---------------------------------------------------------------------------
__global__ void k_wprep(const float* __restrict__ W, unsigned short* __restrict__ Wt,
                        int KK, int H) {
    int bi = blockIdx.x;                 // (m*KK + kk)*4 + cb
    int lane = threadIdx.x;
    int cb = bi & 3;
    int mkk = bi >> 2;
    int kk = mkk % KK, m = mkk / KK;
    int l = cb * 32 + (lane & 31);
    int hbase = kk * 16 + (lane >> 5) * 8;
    unsigned short o[8];
#pragma unroll
    for (int j = 0; j < 8; ++j) {
        int h = hbase + j;
        float v = (h < H) ? W[((size_t)m * H + h) * LDIM + l] : 0.f;
        o[j] = f32_to_bf16(v);
    }
    *(short8*)(Wt + ((size_t)bi * 64 + lane) * 8) = *(const short8*)o;
}

// ---------------------------------------------------------------------------
// OPERAND-SWAPPED GEMM (W = A-operand, XK = B-operand -> D[l, row]).
//   out_acc[row,l] = sum_m s_m(row) * (W[m]^T-ish @ XK^T)[l,row]
// Why the swap: C/D col = lane&31 = batch-row, so the per-row scale s_m is a
// PER-LANE SCALAR (2 regs, 2 loads/m) instead of 8 float4 vector loads into
// 32 regs. Frees ~28 arch VGPRs (R9 was at the exact 256-reg cap -> zero
// scheduler slack) and makes the per-unit vmem pattern uniform.
// Structure: R9's proven ring-4 LDS / raw-barrier / counted-vmcnt skeleton.
//   - gates: uniform vmcnt(10) at every unit end (pattern [2 s + KU stage])
//   - epilogue in float2 (v_pk_fma_f32), s_setprio 1/0 around burst/epilogue
//   - X between layers stored row-major [row][128]; next layer's XK B-frags
//     are plain short8 loads (16B aligned)
// NOTE: (256,2) -> 256 unified regs/wave. (512,4) spilled catastrophically
// in round 3 — do not revisit.
// ---------------------------------------------------------------------------
template <int KK, int KU, bool FIRST, int OFF, bool WRITEX>
__global__ __launch_bounds__(256, 2) void k_gemm(
    const float* __restrict__ x,               // fp32 [B][MF][DDIM]
    const unsigned short* __restrict__ Xprev,  // bf16 [ROWS][LDIM] (unused if FIRST)
    const unsigned short* __restrict__ Wt,     // bf16 [MF][KK][4][64][8]
    unsigned short* __restrict__ Xout,         // bf16 [ROWS][LDIM] (unused if !WRITEX)
    float* __restrict__ out)                   // fp32 [B][384]
{
    constexpr int UPM   = KK / KU;             // units per m (1 or 2)
    constexpr int NU    = MF * UPM;            // total units
    constexpr int SLOTS = (KU == 4) ? 2 : 3;   // reg-ring slots (KU%SLOTS==0)
    constexpr int DIST  = SLOTS;               // prefetch distance

    __shared__ unsigned short slab[4][KU * 2048];   // 4-slot ring

    const int tid  = threadIdx.x;
    const int lane = tid & 63, wave = tid >> 6;
    const int hf   = lane >> 5, r31 = lane & 31;
    const int rowhalf = wave >> 1, colhalf = wave & 1;
    const int b = blockIdx.x * 2 + rowhalf;    // this wave's batch

    // ---- XK fragments (B-operand), once: xk[t][kk], B[k=h][col=row] ----
    bf16x8 xk[2][KK];
    if constexpr (FIRST) {
#pragma unroll
        for (int t = 0; t < 2; ++t)
#pragma unroll
            for (int kk = 0; kk < KK; ++kk) {
                unsigned short tmp[8];
#pragma unroll
                for (int j = 0; j < 8; ++j) {
                    int h = kk * 16 + hf * 8 + j;
                    float v = (h < MF) ? x[((size_t)b * MF + h) * DDIM + t * 32 + r31] : 0.f;
                    tmp[j] = f32_to_bf16(v);
                }
                xk[t][kk] = __builtin_bit_cast(bf16x8, *(const short8*)tmp);
            }
    } else {
#pragma unroll
        for (int t = 0; t < 2; ++t)
#pragma unroll
            for (int kk = 0; kk < KK; ++kk)
                xk[t][kk] = __builtin_bit_cast(bf16x8, *(const short8*)(
                    Xprev + (size_t)(b * 64 + t * 32 + r31) * LDIM + kk * 16 + hf * 8));
    }

    floatx16 acc[2][2] = {};   // [t(row-tile)][cbp(l-tile)], layout D[l,row]

    auto stage = [&](int uu) {                 // stage unit uu (clamped)
        int u = uu < NU ? uu : NU - 1;         // restage of last unit: same bytes
        const unsigned short* src = Wt + (size_t)u * (KU * 2048);
#pragma unroll
        for (int it = 0; it < KU; ++it) {
            int c = it * 256 + tid;
            __builtin_amdgcn_global_load_lds(
                (const __attribute__((address_space(1))) uint32_t*)(src + (size_t)c * 8),
                (__attribute__((address_space(3))) uint32_t*)(&slab[u & 3][(size_t)c * 8]),
                16, 0, 0);
        }
    };

    const int cbg0 = colhalf * 2, cbg1 = colhalf * 2 + 1;
    auto ldfrag = [&](int u, int frag, int cb) {
        return __builtin_bit_cast(bf16x8,
            *(const short8*)(&slab[u & 3][((size_t)(frag * 4 + cb) * 64 + lane) * 8]));
    };

    // ---- prologue: fill 3 ring slots ----
    vmwait<0>();
    stage(0); stage(1); stage(2);
    vmwait<(KU == 4) ? 4 : 3>();               // stage(0,1) retired
    barrier_raw();

    bf16x8 bbuf[SLOTS][2];                     // W A-frag register ring
#pragma unroll
    for (int p = 0; p < SLOTS; ++p) {
        bbuf[p][0] = ldfrag(0, p, cbg0);
        bbuf[p][1] = ldfrag(0, p, cbg1);
    }

    float s0v = 0.f, s1v = 0.f;                // per-lane scalar scales

#pragma unroll 1
    for (int m = 0; m < MF; ++m) {
        floatx16 P[2][2] = {};
#pragma unroll
        for (int kk = 0; kk < KK; ++kk) {
            if (kk % KU == 0) {                // unit top
                barrier_raw();
                asm volatile("s_setprio 1");
                if (kk == 0) {                 // 2 scalar-per-lane scale loads
                    const float* sp = x + ((size_t)b * MF + m) * DDIM + r31;
                    s0v = sp[0];
                    s1v = sp[32];
                }
                stage(m * UPM + kk / KU + 3);  // 3 units ahead in the ring
            }
            const int slot = (KU == 4) ? (kk & 1) : kk;
            P[0][0] = __builtin_amdgcn_mfma_f32_32x32x16_bf16(bbuf[slot][0], xk[0][kk], P[0][0], 0, 0, 0);
            P[1][0] = __builtin_amdgcn_mfma_f32_32x32x16_bf16(bbuf[slot][0], xk[1][kk], P[1][0], 0, 0, 0);
            P[0][1] = __builtin_amdgcn_mfma_f32_32x32x16_bf16(bbuf[slot][1], xk[0][kk], P[0][1], 0, 0, 0);
            P[1][1] = __builtin_amdgcn_mfma_f32_32x32x16_bf16(bbuf[slot][1], xk[1][kk], P[1][1], 0, 0, 0);
            {   // prefetch DIST kk's ahead (reaches across unit/m boundary)
                const int j  = kk + DIST;               // compile-time
                int mm = m + ((j >= KK) ? 1 : 0);
                if (mm > MF - 1) mm = MF - 1;           // clamp (tail: harmless)
                const int jj = (j >= KK) ? (j - KK) : j;
                const int u  = mm * UPM + jj / KU;
                bbuf[slot][0] = ldfrag(u, jj % KU, cbg0);
                bbuf[slot][1] = ldfrag(u, jj % KU, cbg1);
            }
            if (kk % KU == KU - 1) vmwait<10>();   // uniform end-of-unit gate
        }
        asm volatile("s_setprio 0");
        // epilogue: acc += s_t * P, float2 form -> v_pk_fma_f32
#pragma unroll
        for (int t = 0; t < 2; ++t) {
            const float sv = (t == 0) ? s0v : s1v;
            floatx2 s2 = {sv, sv};
#pragma unroll
            for (int cbp = 0; cbp < 2; ++cbp) {
                floatx2*       A = (floatx2*)&acc[t][cbp];
                const floatx2* Q = (const floatx2*)&P[t][cbp];
#pragma unroll
                for (int i = 0; i < 8; ++i) A[i] += s2 * Q[i];
            }
        }
    }

    // ---- store x_next row-major [row][LDIM] (short4 stores) ----
    // D layout: col=lane&31=row-offset; D-row = (j&3)+8*(j>>2)+4*hf = l-offset
    if constexpr (WRITEX) {
#pragma unroll
        for (int t = 0; t < 2; ++t) {
            const size_t rowbase = (size_t)(b * 64 + t * 32 + r31) * LDIM;
#pragma unroll
            for (int cbp = 0; cbp < 2; ++cbp) {
#pragma unroll
                for (int g = 0; g < 4; ++g) {
                    unsigned short o[4];
#pragma unroll
                    for (int i = 0; i < 4; ++i) o[i] = f32_to_bf16(acc[t][cbp][g * 4 + i]);
                    *(short4_t*)(Xout + rowbase + (colhalf * 2 + cbp) * 32 + 8 * g + 4 * hf) =
                        *(const short4_t*)o;
                }
            }
        }
    }

    // ---- fused ps: out[b][OFF+l] = sum_d acc  (sum over t in-lane, then
    //      butterfly over the 32 lanes of each half; all-lane result) ----
#pragma unroll
    for (int cbp = 0; cbp < 2; ++cbp) {
#pragma unroll
        for (int j = 0; j < 16; ++j) {
            float v = acc[0][cbp][j] + acc[1][cbp][j];
            v += __shfl_xor(v, 16);
            v += __shfl_xor(v, 8);
            v += __shfl_xor(v, 4);
            v += __shfl_xor(v, 2);
            v += __shfl_xor(v, 1);
            if (r31 == 0)
                out[(size_t)b * 384 + OFF + (colhalf * 2 + cbp) * 32 +
                    (j & 3) + 8 * (j >> 2) + 4 * hf] = v;
        }
    }
}

// ---------------------------------------------------------------------------
extern "C" void kernel_launch(void* const* d_in, const int* in_sizes, int n_in,
                              void* d_out, int out_size, void* d_ws, size_t ws_size,
                              hipStream_t stream) {
    const float* x  = (const float*)d_in[0];
    const float* W0 = (const float*)d_in[1];
    const float* W1 = (const float*)d_in[2];
    const float* W2 = (const float*)d_in[3];
    float* out = (float*)d_out;

    char* ws = (char*)d_ws;
    size_t off = 0;
    auto alloc = [&](size_t bytes) -> void* {
        void* p = ws + off;
        off += (bytes + 255) & ~(size_t)255;
        return p;
    };
    unsigned short* W0t = (unsigned short*)alloc((size_t)MF * 3 * 2048 * 2);   // 0.5 MB
    unsigned short* W1t = (unsigned short*)alloc((size_t)MF * 8 * 2048 * 2);   // 1.3 MB
    unsigned short* W2t = (unsigned short*)alloc((size_t)MF * 8 * 2048 * 2);   // 1.3 MB
    unsigned short* X1p = (unsigned short*)alloc((size_t)ROWS * LDIM * 2);     // 33.5 MB
    unsigned short* X2p = (unsigned short*)alloc((size_t)ROWS * LDIM * 2);     // 33.5 MB

    k_wprep<<<MF * 3 * 4, 64, 0, stream>>>(W0, W0t, 3, 40);
    k_wprep<<<MF * 8 * 4, 64, 0, stream>>>(W1, W1t, 8, 128);
    k_wprep<<<MF * 8 * 4, 64, 0, stream>>>(W2, W2t, 8, 128);

    k_gemm<3, 3, true,  0,   true ><<<ROWS / 128, 256, 0, stream>>>(x, nullptr, W0t, X1p, out);
    k_gemm<8, 4, false, 128, true ><<<ROWS / 128, 256, 0, stream>>>(x, X1p,     W1t, X2p, out);
    k_gemm<8, 4, false, 256, false><<<ROWS / 128, 256, 0, stream>>>(x, X2p,     W2t, X2p, out);
}

// Round 11
// 438.687 us; speedup vs baseline: 1.0559x; 1.0559x over previous
//
#include <hip/hip_runtime.h>
#include <hip/hip_bf16.h>
#include <cstdint>

// Problem constants
#define BATCH 2048
#define MF    40                 // num fields
#define DDIM  64                 // embedding dim
#define LDIM  128                // hidden size per CIN layer
#define ROWS  (BATCH * DDIM)     // 131072 (b,d) rows

typedef __attribute__((ext_vector_type(4)))  short    short4_t;
typedef __attribute__((ext_vector_type(8)))  short    short8;
typedef __attribute__((ext_vector_type(8)))  __bf16   bf16x8;
typedef __attribute__((ext_vector_type(2)))  float    floatx2;
typedef __attribute__((ext_vector_type(16))) float    floatx16;

__device__ __forceinline__ unsigned short f32_to_bf16(float f) {
    union { float f; uint32_t u; } v; v.f = f;
    uint32_t u = v.u;
    uint32_t r = (u + 0x7fffu + ((u >> 16) & 1u)) >> 16;   // RNE
    return (unsigned short)r;
}

// raw barrier: execution sync WITHOUT __syncthreads' vmcnt(0)/lgkmcnt(0) drain
__device__ __forceinline__ void barrier_raw() {
    asm volatile("s_barrier" ::: "memory");
}
__device__ __forceinline__ void lgkmwait0() {
    asm volatile("s_waitcnt lgkmcnt(0)" ::: "memory");
}
template <int N> __device__ __forceinline__ void vmwait() {
    if constexpr (N == 0)  asm volatile("s_waitcnt vmcnt(0)"  ::: "memory");
    if constexpr (N == 4)  asm volatile("s_waitcnt vmcnt(4)"  ::: "memory");
    if constexpr (N == 6)  asm volatile("s_waitcnt vmcnt(6)"  ::: "memory");
    if constexpr (N == 10) asm volatile("s_waitcnt vmcnt(10)" ::: "memory");
}

// ---------------------------------------------------------------------------
// W prep, all three layers in ONE launch (saves 2 launch gaps).
//   Wt[m][kk][cb][lane][j] = W[m][ kk*16 + (lane>>5)*8 + j ][ cb*32 + (lane&31) ]
// W0 is padded to KK=4 (h in [40,64) -> 0): zero MFMA terms are exact, and
// the K-loop/ring becomes uniform (KU=4 units everywhere).
// ---------------------------------------------------------------------------
__global__ void k_wprep_all(const float* __restrict__ W0, const float* __restrict__ W1,
                            const float* __restrict__ W2,
                            unsigned short* __restrict__ W0t,
                            unsigned short* __restrict__ W1t,
                            unsigned short* __restrict__ W2t) {
    int bi = blockIdx.x;                 // W0: 640 blocks, W1/W2: 1280 each
    const float* W; unsigned short* Wt; int KK, H;
    if (bi < 640)       { W = W0; Wt = W0t; KK = 4; H = 40; }
    else if (bi < 1920) { bi -= 640;  W = W1; Wt = W1t; KK = 8; H = 128; }
    else                { bi -= 1920; W = W2; Wt = W2t; KK = 8; H = 128; }
    int lane = threadIdx.x;
    int cb = bi & 3;
    int mkk = bi >> 2;
    int kk = mkk % KK, m = mkk / KK;
    int l = cb * 32 + (lane & 31);
    int hbase = kk * 16 + (lane >> 5) * 8;
    unsigned short o[8];
#pragma unroll
    for (int j = 0; j < 8; ++j) {
        int h = hbase + j;
        float v = (h < H) ? W[((size_t)m * H + h) * LDIM + l] : 0.f;
        o[j] = f32_to_bf16(v);
    }
    *(short8*)(Wt + (((size_t)(m * KK + kk) * 4 + cb) * 64 + lane) * 8) = *(const short8*)o;
}

// ---------------------------------------------------------------------------
// One layer's K-loop: R10's proven ring-4 / raw-barrier / counted-vmcnt body.
// Operand-swapped: W = A-operand, XK = B-operand -> D[l, row]; per-row scale
// s_m is a per-lane scalar applied in a tiny float2 epilogue.
// KK=4 (L0, UPM=1, gate 6) or KK=8 (L1/L2, UPM=2, gate 10).
// ---------------------------------------------------------------------------
template <int KK>
__device__ __forceinline__ void layer_loop(
    const unsigned short* __restrict__ Wt,     // bf16 [MF][KK][4][64][8]
    const float* __restrict__ x, int b,
    int lane, int hf, int r31, int cbg0, int cbg1,
    unsigned short* slabf,                     // &slab[0][0]: 4 slots x 8192 shorts
    bf16x8 (&xk)[2][8], floatx16 (&acc)[2][2])
{
    constexpr int UPM  = KK / 4;               // units per m
    constexpr int NU   = MF * UPM;             // total units (16 KB each)
    constexpr int GATE = (KK == 8) ? 10 : 6;   // = vmem insts per m (uniform)

    auto stage = [&](int uu) {                 // stage unit uu (clamped: same bytes)
        int u = uu < NU ? uu : NU - 1;
        const unsigned short* src = Wt + (size_t)u * 8192;
        const int tid = threadIdx.x;
#pragma unroll
        for (int it = 0; it < 4; ++it) {
            int c = it * 256 + tid;
            __builtin_amdgcn_global_load_lds(
                (const __attribute__((address_space(1))) uint32_t*)(src + (size_t)c * 8),
                (__attribute__((address_space(3))) uint32_t*)(&slabf[(size_t)(u & 3) * 8192 + (size_t)c * 8]),
                16, 0, 0);
        }
    };
    auto ldfrag = [&](int u, int frag, int cb) {
        return __builtin_bit_cast(bf16x8, *(const short8*)(
            &slabf[(size_t)(u & 3) * 8192 + ((size_t)(frag * 4 + cb) * 64 + lane) * 8]));
    };

    acc[0][0] = floatx16{}; acc[0][1] = floatx16{};
    acc[1][0] = floatx16{}; acc[1][1] = floatx16{};

    // prologue: fill 3 ring slots; units 0,1 retired before priming
    vmwait<0>();
    stage(0); stage(1); stage(2);
    vmwait<4>();
    barrier_raw();

    bf16x8 bbuf[2][2];                         // W A-frag register ring
#pragma unroll
    for (int p = 0; p < 2; ++p) {
        bbuf[p][0] = ldfrag(0, p, cbg0);
        bbuf[p][1] = ldfrag(0, p, cbg1);
    }

    float s0v = 0.f, s1v = 0.f;

#pragma unroll 1
    for (int m = 0; m < MF; ++m) {
        floatx16 P[2][2] = {};
#pragma unroll
        for (int kk = 0; kk < KK; ++kk) {
            if (kk % 4 == 0) {                 // unit top
                barrier_raw();
                asm volatile("s_setprio 1");
                if (kk == 0) {                 // 2 per-lane scalar scale loads
                    const float* sp = x + ((size_t)b * MF + m) * DDIM + r31;
                    s0v = sp[0];
                    s1v = sp[32];
                }
                stage(m * UPM + kk / 4 + 3);   // 3 units ahead in the ring
            }
            const int slot = kk & 1;
            P[0][0] = __builtin_amdgcn_mfma_f32_32x32x16_bf16(bbuf[slot][0], xk[0][kk], P[0][0], 0, 0, 0);
            P[1][0] = __builtin_amdgcn_mfma_f32_32x32x16_bf16(bbuf[slot][0], xk[1][kk], P[1][0], 0, 0, 0);
            P[0][1] = __builtin_amdgcn_mfma_f32_32x32x16_bf16(bbuf[slot][1], xk[0][kk], P[0][1], 0, 0, 0);
            P[1][1] = __builtin_amdgcn_mfma_f32_32x32x16_bf16(bbuf[slot][1], xk[1][kk], P[1][1], 0, 0, 0);
            {   // prefetch 2 kk ahead (crosses unit/m boundary; all compile-time)
                const int j  = kk + 2;
                int mm = m + ((j >= KK) ? 1 : 0);
                if (mm > MF - 1) mm = MF - 1;
                const int jj = (j >= KK) ? (j - KK) : j;
                const int u  = mm * UPM + jj / 4;
                bbuf[slot][0] = ldfrag(u, jj % 4, cbg0);
                bbuf[slot][1] = ldfrag(u, jj % 4, cbg1);
            }
            if (kk % 4 == 3) vmwait<GATE>();   // uniform end-of-unit gate
        }
        asm volatile("s_setprio 0");
        // epilogue: acc += s_t * P (float2 -> v_pk_fma_f32)
#pragma unroll
        for (int t = 0; t < 2; ++t) {
            const float sv = (t == 0) ? s0v : s1v;
            floatx2 s2 = {sv, sv};
#pragma unroll
            for (int cbp = 0; cbp < 2; ++cbp) {
                floatx2*       A = (floatx2*)&acc[t][cbp];
                const floatx2* Q = (const floatx2*)&P[t][cbp];
#pragma unroll
                for (int i = 0; i < 8; ++i) A[i] += s2 * Q[i];
            }
        }
    }
}

// ---------------------------------------------------------------------------
// Fused 3-layer CIN kernel. Block = 256 thr = 4 waves (2x2), 2 batches x all
// 128 l's per block; grid 1024 = 2 blocks/CU. X intermediates NEVER touch
// global: at each layer boundary, waves write their D-layout acc into LDS
// (overlaying ring slots 0-1) in exact reader B-fragment order, then reload
// xk fragments. ps outputs fused per layer (butterfly shuffle).
// NOTE: (256,2) -> 256 unified regs/wave. (512,4) spilled catastrophically
// in round 3 — do not revisit.
// ---------------------------------------------------------------------------
__global__ __launch_bounds__(256, 2) void k_cin(
    const float* __restrict__ x,               // fp32 [B][MF][DDIM]
    const unsigned short* __restrict__ W0t,    // bf16 [MF][4][4][64][8] (padded)
    const unsigned short* __restrict__ W1t,    // bf16 [MF][8][4][64][8]
    const unsigned short* __restrict__ W2t,    // bf16 [MF][8][4][64][8]
    float* __restrict__ out)                   // fp32 [B][384]
{
    __shared__ unsigned short slab[4][8192];   // 4 x 16 KB W-ring; slots 0-1
                                               // double as the 32 KB X-exchange
    unsigned short* slabf = &slab[0][0];

    const int tid  = threadIdx.x;
    const int lane = tid & 63, wave = tid >> 6;
    const int hf   = lane >> 5, r31 = lane & 31;
    const int rowhalf = wave >> 1, colhalf = wave & 1;
    const int b = blockIdx.x * 2 + rowhalf;    // this wave's batch
    const int cbg0 = colhalf * 2, cbg1 = colhalf * 2 + 1;

    bf16x8   xk[2][8];                         // B-operand fragments
    floatx16 acc[2][2];                        // [t(row-tile)][cbp], D[l,row]

    // ---- ps: out[b][OFF+l] = sum over all 64 d (butterfly across lanes) ----
    auto write_ps = [&](int OFF) {
#pragma unroll
        for (int cbp = 0; cbp < 2; ++cbp) {
#pragma unroll
            for (int j = 0; j < 16; ++j) {
                float v = acc[0][cbp][j] + acc[1][cbp][j];
                v += __shfl_xor(v, 16);
                v += __shfl_xor(v, 8);
                v += __shfl_xor(v, 4);
                v += __shfl_xor(v, 2);
                v += __shfl_xor(v, 1);
                if (r31 == 0)
                    out[(size_t)b * 384 + OFF + (colhalf * 2 + cbp) * 32 +
                        (j & 3) + 8 * (j >> 2) + 4 * hf] = v;
            }
        }
    };

    // ---- layer boundary: acc -> LDS (reader frag order) -> xk ----
    // Writer element: row = t*32+r31, l = colhalf*64 + cbp*32 + 8g + 4hf + i
    //   => kk = colhalf*4 + cbp*2 + (g>>1), hfr = g&1, j = 4hf+i
    // Xf addr (shorts): rowhalf*8192 + ((t*8+kk)*64 + hfr*32 + r31)*8 + 4hf
    auto exchange = [&]() {
        vmwait<0>();                           // drain ring staging + ps stores
        barrier_raw();
#pragma unroll
        for (int t = 0; t < 2; ++t)
#pragma unroll
            for (int cbp = 0; cbp < 2; ++cbp)
#pragma unroll
                for (int g = 0; g < 4; ++g) {
                    unsigned short o[4];
#pragma unroll
                    for (int i = 0; i < 4; ++i) o[i] = f32_to_bf16(acc[t][cbp][g * 4 + i]);
                    const int kk  = colhalf * 4 + cbp * 2 + (g >> 1);
                    const int hfr = g & 1;
                    *(short4_t*)(&slabf[(size_t)rowhalf * 8192 +
                        ((size_t)(t * 8 + kk) * 64 + hfr * 32 + r31) * 8 + 4 * hf]) =
                        *(const short4_t*)o;
                }
        lgkmwait0();                           // writes committed to LDS
        barrier_raw();
#pragma unroll
        for (int t = 0; t < 2; ++t)
#pragma unroll
            for (int kk = 0; kk < 8; ++kk)
                xk[t][kk] = __builtin_bit_cast(bf16x8, *(const short8*)(
                    &slabf[(size_t)rowhalf * 8192 + ((size_t)(t * 8 + kk) * 64 + lane) * 8]));
        lgkmwait0();                           // reads in regs before restaging
        barrier_raw();
    };

    // ---- layer 0: xk from original x (KK=4 padded, h<MF else 0) ----
#pragma unroll
    for (int t = 0; t < 2; ++t)
#pragma unroll
        for (int kk = 0; kk < 4; ++kk) {
            unsigned short tmp[8];
#pragma unroll
            for (int j = 0; j < 8; ++j) {
                int h = kk * 16 + hf * 8 + j;
                float v = (h < MF) ? x[((size_t)b * MF + h) * DDIM + t * 32 + r31] : 0.f;
                tmp[j] = f32_to_bf16(v);
            }
            xk[t][kk] = __builtin_bit_cast(bf16x8, *(const short8*)tmp);
        }

    layer_loop<4>(W0t, x, b, lane, hf, r31, cbg0, cbg1, slabf, xk, acc);
    write_ps(0);
    exchange();

    layer_loop<8>(W1t, x, b, lane, hf, r31, cbg0, cbg1, slabf, xk, acc);
    write_ps(128);
    exchange();

    layer_loop<8>(W2t, x, b, lane, hf, r31, cbg0, cbg1, slabf, xk, acc);
    write_ps(256);
}

// ---------------------------------------------------------------------------
extern "C" void kernel_launch(void* const* d_in, const int* in_sizes, int n_in,
                              void* d_out, int out_size, void* d_ws, size_t ws_size,
                              hipStream_t stream) {
    const float* x  = (const float*)d_in[0];
    const float* W0 = (const float*)d_in[1];
    const float* W1 = (const float*)d_in[2];
    const float* W2 = (const float*)d_in[3];
    float* out = (float*)d_out;

    char* ws = (char*)d_ws;
    size_t off = 0;
    auto alloc = [&](size_t bytes) -> void* {
        void* p = ws + off;
        off += (bytes + 255) & ~(size_t)255;
        return p;
    };
    unsigned short* W0t = (unsigned short*)alloc((size_t)MF * 4 * 2048 * 2);   // 0.66 MB
    unsigned short* W1t = (unsigned short*)alloc((size_t)MF * 8 * 2048 * 2);   // 1.31 MB
    unsigned short* W2t = (unsigned short*)alloc((size_t)MF * 8 * 2048 * 2);   // 1.31 MB

    k_wprep_all<<<3200, 64, 0, stream>>>(W0, W1, W2, W0t, W1t, W2t);
    k_cin<<<ROWS / 128, 256, 0, stream>>>(x, W0t, W1t, W2t, out);
}